// Round 1
// baseline (1825.307 us; speedup 1.0000x reference)
//
#include <hip/hip_runtime.h>

#define BB 4
#define SS 2048
#define DDIM 512
#define HH 8
#define MTOK (BB*SS)   // 8192
#define BHN (BB*HH)    // 32

typedef _Float16 f16;
typedef __attribute__((ext_vector_type(8))) _Float16 half8;
typedef __attribute__((ext_vector_type(4))) float float4v;

__device__ __forceinline__ float4v mfma16(half8 a, half8 b, float4v c) {
  return __builtin_amdgcn_mfma_f32_16x16x32_f16(a, b, c, 0, 0, 0);
}

__device__ __forceinline__ half8 cvt8(float4v a, float4v b) {
  half8 r;
  r[0] = (f16)a[0]; r[1] = (f16)a[1]; r[2] = (f16)a[2]; r[3] = (f16)a[3];
  r[4] = (f16)b[0]; r[5] = (f16)b[1]; r[6] = (f16)b[2]; r[7] = (f16)b[3];
  return r;
}

// ---------------- mask dtype detection ----------------
// If the bool mask is stored as 1 byte/elem, a 32-bit word holds 4 bools and
// with ~10% density some word in the first 64K words has a nonzero byte above
// byte0 (value > 1) with overwhelming probability. If stored as int32 0/1,
// every word is <= 1. flag=1 -> byte mask, flag=0 -> int32 mask.
__global__ __launch_bounds__(256) void detect_mask_kernel(
    const unsigned int* __restrict__ m, unsigned int* __restrict__ flag) {
  unsigned int v = 0;
  for (int j = threadIdx.x; j < 65536; j += 256)
    if (m[j] > 1u) v = 1u;
  if (v) atomicOr(flag, 1u);
}

// ---------------- GEMM: [8192,512] x [512,512]^T ----------------
// Out[m,n] = sum_k A[m,k] * W[n,k].  Both operands K-contiguous (B^T form).
// AHALF: A is f16 (else fp32, converted while staging). OUTHALF: f16 out.
template<int AHALF, int OUTHALF>
__global__ __launch_bounds__(256) void gemm512(const void* __restrict__ Ain,
                                               const float* __restrict__ W,
                                               void* __restrict__ Outv) {
  __shared__ f16 As[128][40];
  __shared__ f16 Bs[128][40];
  const int t = threadIdx.x;
  const int bm = blockIdx.x * 128;
  const int bn = blockIdx.y * 128;
  const int w = t >> 6, ln = t & 63;
  const int wr = w >> 1, wc = w & 1;
  const int lr = ln & 15, lg = ln >> 4;
  const int srow = t >> 1, scol = (t & 1) * 16;

  float4v acc[4][4] = {};

  for (int k0 = 0; k0 < 512; k0 += 32) {
    // stage A
    if (AHALF) {
      const f16* ap = (const f16*)Ain + (size_t)(bm + srow) * 512 + k0 + scol;
      *(half8*)&As[srow][scol]     = *(const half8*)(ap);
      *(half8*)&As[srow][scol + 8] = *(const half8*)(ap + 8);
    } else {
      const float* ap = (const float*)Ain + (size_t)(bm + srow) * 512 + k0 + scol;
      float4v x0 = *(const float4v*)ap,       x1 = *(const float4v*)(ap + 4);
      float4v x2 = *(const float4v*)(ap + 8), x3 = *(const float4v*)(ap + 12);
      *(half8*)&As[srow][scol]     = cvt8(x0, x1);
      *(half8*)&As[srow][scol + 8] = cvt8(x2, x3);
    }
    // stage W (always fp32 -> f16)
    {
      const float* wp = W + (size_t)(bn + srow) * 512 + k0 + scol;
      float4v x0 = *(const float4v*)wp,       x1 = *(const float4v*)(wp + 4);
      float4v x2 = *(const float4v*)(wp + 8), x3 = *(const float4v*)(wp + 12);
      *(half8*)&Bs[srow][scol]     = cvt8(x0, x1);
      *(half8*)&Bs[srow][scol + 8] = cvt8(x2, x3);
    }
    __syncthreads();
    half8 af[4], bf[4];
    #pragma unroll
    for (int m = 0; m < 4; m++) af[m] = *(const half8*)&As[wr * 64 + m * 16 + lr][lg * 8];
    #pragma unroll
    for (int n = 0; n < 4; n++) bf[n] = *(const half8*)&Bs[wc * 64 + n * 16 + lr][lg * 8];
    #pragma unroll
    for (int m = 0; m < 4; m++)
      #pragma unroll
      for (int n = 0; n < 4; n++) acc[m][n] = mfma16(af[m], bf[n], acc[m][n]);
    __syncthreads();
  }

  #pragma unroll
  for (int m = 0; m < 4; m++) {
    int row = bm + wr * 64 + m * 16 + lg * 4;
    #pragma unroll
    for (int n = 0; n < 4; n++) {
      int col = bn + wc * 64 + n * 16 + lr;
      #pragma unroll
      for (int r = 0; r < 4; r++) {
        if (OUTHALF) ((f16*)Outv)[(size_t)(row + r) * 512 + col] = (f16)acc[m][n][r];
        else         ((float*)Outv)[(size_t)(row + r) * 512 + col] = acc[m][n][r];
      }
    }
  }
}

// ---------------- V transpose: Vp[tok,512] -> Vtt[bh][dv=64][tok=2048] ----------------
__global__ __launch_bounds__(256) void transpose_v(const f16* __restrict__ Vp,
                                                   f16* __restrict__ Vtt) {
  __shared__ f16 tile[128][72];
  const int t = threadIdx.x;
  const int bh = blockIdx.x, tb = blockIdx.y * 128;
  const int b = bh >> 3, h = bh & 7;
  {
    int tok = t >> 1, c0 = (t & 1) * 32;
    const f16* src = Vp + (size_t)(b * SS + tb + tok) * 512 + h * 64 + c0;
    #pragma unroll
    for (int j = 0; j < 4; j++)
      *(half8*)&tile[tok][c0 + j * 8] = *(const half8*)(src + j * 8);
  }
  __syncthreads();
  {
    int dv = t >> 2, k0 = (t & 3) * 32;
    f16 buf[32];
    #pragma unroll
    for (int j = 0; j < 32; j++) buf[j] = tile[k0 + j][dv];
    f16* dst = Vtt + ((size_t)bh * 64 + dv) * 2048 + tb + k0;
    #pragma unroll
    for (int j = 0; j < 4; j++)
      *(half8*)(dst + j * 8) = *(half8*)&buf[j * 8];
  }
}

// ---------------- attention phases ----------------
// PHASE 1: compute row sums l (denominators).  PHASE 2: write normalized attn
// + fused PV into ctx.  Block = 256 thr (4 waves), tile 128 q x 128 k.
// LDS layout (dynamic): Ks [128][72] at 0; phase2: Ps [128][136] at 0 (aliases
// Ks; written after all Ks reads), Vs [64][136] at 34816, red[128] at
// 52224 (phase2) / 18432 (phase1).
template<int PHASE>
__global__ __launch_bounds__(256) void attn_phase(
    const f16* __restrict__ Qp, const f16* __restrict__ Kp,
    const f16* __restrict__ Vtt, const float* __restrict__ other,
    const unsigned char* __restrict__ mask8, const int* __restrict__ mask32,
    const unsigned int* __restrict__ flag, float* __restrict__ lsum,
    float* __restrict__ attn_out, f16* __restrict__ ctx) {
  extern __shared__ char smem[];
  f16* Ks = (f16*)smem;                       // [128][72]
  f16* Ps = (f16*)smem;                       // [128][136] (phase2)
  f16* Vs = (f16*)(smem + 34816);             // [64][136]  (phase2)
  float* red = (PHASE == 1) ? (float*)(smem + 18432) : (float*)(smem + 52224);

  const int t = threadIdx.x;
  const int bh = blockIdx.x;
  const int b = bh >> 3, h = bh & 7;
  const int qblk = blockIdx.y * 128;
  const int w = t >> 6, ln = t & 63;
  const int wr = w >> 1, wc = w & 1;
  const int lr = ln & 15, lg = ln >> 4;
  const bool use8 = (*flag) != 0;

  // Q fragments in registers (per-wave 64 q-rows, dk=64 -> 2 k-steps)
  half8 qf[4][2];
  #pragma unroll
  for (int m = 0; m < 4; m++) {
    const f16* qp = Qp + (size_t)(b * SS + qblk + wr * 64 + m * 16 + lr) * 512 + h * 64 + lg * 8;
    qf[m][0] = *(const half8*)qp;
    qf[m][1] = *(const half8*)(qp + 32);
  }

  float rs[4][4];
  float invl[4][4];
  if (PHASE == 1) {
    #pragma unroll
    for (int m = 0; m < 4; m++)
      #pragma unroll
      for (int r = 0; r < 4; r++) rs[m][r] = 0.f;
    if (t < 128) red[t] = 0.f;
  } else {
    if (t < 128) red[t] = 1.0f / lsum[(size_t)bh * SS + qblk + t];
    __syncthreads();
    #pragma unroll
    for (int m = 0; m < 4; m++)
      #pragma unroll
      for (int r = 0; r < 4; r++) invl[m][r] = red[wr * 64 + m * 16 + lg * 4 + r];
  }
  float4v cacc[2][4] = {};

  for (int kt = 0; kt < 16; kt++) {
    const int kb = kt * 128;
    __syncthreads();  // prev-iter LDS consumers done before restaging
    {
      int sr = t >> 1, c0 = (t & 1) * 32;
      const f16* kp = Kp + (size_t)(b * SS + kb + sr) * 512 + h * 64 + c0;
      f16* kd = Ks + sr * 72 + c0;
      #pragma unroll
      for (int j = 0; j < 4; j++) *(half8*)(kd + j * 8) = *(const half8*)(kp + j * 8);
      if (PHASE == 2) {
        int dv = t >> 2, tk = (t & 3) * 32;
        const f16* vp = Vtt + ((size_t)bh * 64 + dv) * 2048 + kb + tk;
        f16* vd = Vs + dv * 136 + tk;
        #pragma unroll
        for (int j = 0; j < 4; j++) *(half8*)(vd + j * 8) = *(const half8*)(vp + j * 8);
      }
    }
    __syncthreads();
    // QK^T
    float4v sacc[4][4] = {};
    #pragma unroll
    for (int ks = 0; ks < 2; ks++) {
      half8 kf[4];
      #pragma unroll
      for (int n = 0; n < 4; n++)
        kf[n] = *(const half8*)(Ks + (wc * 64 + n * 16 + lr) * 72 + ks * 32 + lg * 8);
      #pragma unroll
      for (int m = 0; m < 4; m++)
        #pragma unroll
        for (int n = 0; n < 4; n++) sacc[m][n] = mfma16(qf[m][ks], kf[n], sacc[m][n]);
    }
    __syncthreads();  // all Ks reads complete (Ps aliases Ks)
    // epilogue: scale + bias + mask + exp
    #pragma unroll
    for (int m = 0; m < 4; m++) {
      #pragma unroll
      for (int r = 0; r < 4; r++) {
        const int ql = qblk + wr * 64 + m * 16 + lg * 4 + r;
        const size_t rowo = ((size_t)b * SS + ql) * SS + kb;
        #pragma unroll
        for (int n = 0; n < 4; n++) {
          const int kc = wc * 64 + n * 16 + lr;
          float sc = sacc[m][n][r] * 0.125f + other[rowo + kc];
          bool mk = use8 ? (mask8[rowo + kc] != 0) : (mask32[rowo + kc] != 0);
          float p = mk ? 0.0f : __expf(sc);
          if (PHASE == 1) {
            rs[m][r] += p;
          } else {
            float av = p * invl[m][r];
            attn_out[((size_t)bh * SS + ql) * SS + kb + kc] = av;
            Ps[(wr * 64 + m * 16 + lg * 4 + r) * 136 + kc] = (f16)av;
          }
        }
      }
    }
    if (PHASE == 2) {
      __syncthreads();  // Ps + Vs ready
      #pragma unroll
      for (int ks = 0; ks < 4; ks++) {
        half8 pf[2], vf[4];
        #pragma unroll
        for (int mm = 0; mm < 2; mm++)
          pf[mm] = *(const half8*)(Ps + (w * 32 + mm * 16 + lr) * 136 + ks * 32 + lg * 8);
        #pragma unroll
        for (int n = 0; n < 4; n++)
          vf[n] = *(const half8*)(Vs + (n * 16 + lr) * 136 + ks * 32 + lg * 8);
        #pragma unroll
        for (int mm = 0; mm < 2; mm++)
          #pragma unroll
          for (int n = 0; n < 4; n++) cacc[mm][n] = mfma16(pf[mm], vf[n], cacc[mm][n]);
      }
    }
  }

  if (PHASE == 1) {
    #pragma unroll
    for (int m = 0; m < 4; m++) {
      #pragma unroll
      for (int r = 0; r < 4; r++) {
        float v = rs[m][r];
        v += __shfl_xor(v, 1); v += __shfl_xor(v, 2);
        v += __shfl_xor(v, 4); v += __shfl_xor(v, 8);
        if (lr == 0) atomicAdd(&red[wr * 64 + m * 16 + lg * 4 + r], v);
      }
    }
    __syncthreads();
    if (t < 128) lsum[(size_t)bh * SS + qblk + t] = red[t];
  } else {
    #pragma unroll
    for (int mm = 0; mm < 2; mm++) {
      #pragma unroll
      for (int n = 0; n < 4; n++) {
        #pragma unroll
        for (int r = 0; r < 4; r++) {
          ctx[(size_t)(b * SS + qblk + w * 32 + mm * 16 + lg * 4 + r) * 512 +
              h * 64 + n * 16 + lr] = (f16)cacc[mm][n][r];
        }
      }
    }
  }
}

extern "C" void kernel_launch(void* const* d_in, const int* in_sizes, int n_in,
                              void* d_out, int out_size, void* d_ws, size_t ws_size,
                              hipStream_t stream) {
  const float* inQ   = (const float*)d_in[0];
  const float* inK   = (const float*)d_in[1];
  const float* inV   = (const float*)d_in[2];
  const void*  mask  = d_in[3];
  const float* other = (const float*)d_in[4];
  const float* WQ    = (const float*)d_in[5];
  const float* WK    = (const float*)d_in[6];
  const float* WV    = (const float*)d_in[7];
  const float* WF    = (const float*)d_in[8];

  char* ws = (char*)d_ws;
  size_t off = 0;
  unsigned int* flag = (unsigned int*)(ws + off); off += 256;
  f16* Qp  = (f16*)(ws + off); off += (size_t)MTOK * 512 * 2;
  f16* Kp  = (f16*)(ws + off); off += (size_t)MTOK * 512 * 2;
  f16* Vp  = (f16*)(ws + off); off += (size_t)MTOK * 512 * 2;
  f16* Vtt = (f16*)(ws + off); off += (size_t)MTOK * 512 * 2;
  float* lsum = (float*)(ws + off); off += (size_t)BHN * SS * 4;
  f16* ctx = (f16*)(ws + off); off += (size_t)MTOK * 512 * 2;
  if (ws_size < off) return;  // scratch too small: bail (detectable as failure)

  float* outp  = (float*)d_out;
  float* attnp = outp + (size_t)MTOK * DDIM;

  hipMemsetAsync(flag, 0, 256, stream);
  detect_mask_kernel<<<1, 256, 0, stream>>>((const unsigned int*)mask, flag);

  dim3 pg(64, 4);
  gemm512<0, 1><<<pg, 256, 0, stream>>>(inQ, WQ, Qp);
  gemm512<0, 1><<<pg, 256, 0, stream>>>(inK, WK, Kp);
  gemm512<0, 1><<<pg, 256, 0, stream>>>(inV, WV, Vp);
  transpose_v<<<dim3(32, 16), 256, 0, stream>>>(Vp, Vtt);

  attn_phase<1><<<dim3(32, 16), 256, 18944, stream>>>(
      Qp, Kp, Vtt, other, (const unsigned char*)mask, (const int*)mask, flag,
      lsum, attnp, ctx);
  attn_phase<2><<<dim3(32, 16), 256, 52736, stream>>>(
      Qp, Kp, Vtt, other, (const unsigned char*)mask, (const int*)mask, flag,
      lsum, attnp, ctx);

  gemm512<1, 0><<<pg, 256, 0, stream>>>(ctx, WF, outp);
}

// Round 2
// 925.345 us; speedup vs baseline: 1.9726x; 1.9726x over previous
//
#include <hip/hip_runtime.h>

#define BB 4
#define SS 2048
#define DDIM 512
#define HH 8
#define MTOK (BB*SS)   // 8192
#define BHN (BB*HH)    // 32

typedef _Float16 f16;
typedef __attribute__((ext_vector_type(8))) _Float16 half8;
typedef __attribute__((ext_vector_type(4))) _Float16 half4;
typedef __attribute__((ext_vector_type(4))) float float4v;
typedef __attribute__((ext_vector_type(4))) int int4v;

__device__ __forceinline__ float4v mfma16(half8 a, half8 b, float4v c) {
  return __builtin_amdgcn_mfma_f32_16x16x32_f16(a, b, c, 0, 0, 0);
}

__device__ __forceinline__ half8 cvt8(float4v a, float4v b) {
  half8 r;
  r[0] = (f16)a[0]; r[1] = (f16)a[1]; r[2] = (f16)a[2]; r[3] = (f16)a[3];
  r[4] = (f16)b[0]; r[5] = (f16)b[1]; r[6] = (f16)b[2]; r[7] = (f16)b[3];
  return r;
}

// ---------------- mask dtype detection ----------------
__global__ __launch_bounds__(256) void detect_mask_kernel(
    const unsigned int* __restrict__ m, unsigned int* __restrict__ flag) {
  unsigned int v = 0;
  for (int j = threadIdx.x; j < 65536; j += 256)
    if (m[j] > 1u) v = 1u;
  if (v) atomicOr(flag, 1u);
}

// ---------------- GEMM: [8192,512] x [512,512]^T ----------------
template<int AHALF, int OUTHALF>
__global__ __launch_bounds__(256) void gemm512(const void* __restrict__ Ain,
                                               const float* __restrict__ W,
                                               void* __restrict__ Outv) {
  __shared__ f16 As[128][40];
  __shared__ f16 Bs[128][40];
  const int t = threadIdx.x;
  const int bm = blockIdx.x * 128;
  const int bn = blockIdx.y * 128;
  const int w = t >> 6, ln = t & 63;
  const int wr = w >> 1, wc = w & 1;
  const int lr = ln & 15, lg = ln >> 4;
  const int srow = t >> 1, scol = (t & 1) * 16;

  float4v acc[4][4] = {};

  for (int k0 = 0; k0 < 512; k0 += 32) {
    if (AHALF) {
      const f16* ap = (const f16*)Ain + (size_t)(bm + srow) * 512 + k0 + scol;
      *(half8*)&As[srow][scol]     = *(const half8*)(ap);
      *(half8*)&As[srow][scol + 8] = *(const half8*)(ap + 8);
    } else {
      const float* ap = (const float*)Ain + (size_t)(bm + srow) * 512 + k0 + scol;
      float4v x0 = *(const float4v*)ap,       x1 = *(const float4v*)(ap + 4);
      float4v x2 = *(const float4v*)(ap + 8), x3 = *(const float4v*)(ap + 12);
      *(half8*)&As[srow][scol]     = cvt8(x0, x1);
      *(half8*)&As[srow][scol + 8] = cvt8(x2, x3);
    }
    {
      const float* wp = W + (size_t)(bn + srow) * 512 + k0 + scol;
      float4v x0 = *(const float4v*)wp,       x1 = *(const float4v*)(wp + 4);
      float4v x2 = *(const float4v*)(wp + 8), x3 = *(const float4v*)(wp + 12);
      *(half8*)&Bs[srow][scol]     = cvt8(x0, x1);
      *(half8*)&Bs[srow][scol + 8] = cvt8(x2, x3);
    }
    __syncthreads();
    half8 af[4], bf[4];
    #pragma unroll
    for (int m = 0; m < 4; m++) af[m] = *(const half8*)&As[wr * 64 + m * 16 + lr][lg * 8];
    #pragma unroll
    for (int n = 0; n < 4; n++) bf[n] = *(const half8*)&Bs[wc * 64 + n * 16 + lr][lg * 8];
    #pragma unroll
    for (int m = 0; m < 4; m++)
      #pragma unroll
      for (int n = 0; n < 4; n++) acc[m][n] = mfma16(af[m], bf[n], acc[m][n]);
    __syncthreads();
  }

  #pragma unroll
  for (int m = 0; m < 4; m++) {
    int row = bm + wr * 64 + m * 16 + lg * 4;
    #pragma unroll
    for (int n = 0; n < 4; n++) {
      int col = bn + wc * 64 + n * 16 + lr;
      #pragma unroll
      for (int r = 0; r < 4; r++) {
        if (OUTHALF) ((f16*)Outv)[(size_t)(row + r) * 512 + col] = (f16)acc[m][n][r];
        else         ((float*)Outv)[(size_t)(row + r) * 512 + col] = acc[m][n][r];
      }
    }
  }
}

// ---------------- V transpose: Vp[tok,512] -> Vtt[bh][dv=64][tok=2048] ----------------
__global__ __launch_bounds__(256) void transpose_v(const f16* __restrict__ Vp,
                                                   f16* __restrict__ Vtt) {
  __shared__ f16 tile[128][72];
  const int t = threadIdx.x;
  const int bh = blockIdx.x, tb = blockIdx.y * 128;
  const int b = bh >> 3, h = bh & 7;
  {
    int tok = t >> 1, c0 = (t & 1) * 32;
    const f16* src = Vp + (size_t)(b * SS + tb + tok) * 512 + h * 64 + c0;
    #pragma unroll
    for (int j = 0; j < 4; j++)
      *(half8*)&tile[tok][c0 + j * 8] = *(const half8*)(src + j * 8);
  }
  __syncthreads();
  {
    int dv = t >> 2, k0 = (t & 3) * 32;
    f16 buf[32];
    #pragma unroll
    for (int j = 0; j < 32; j++) buf[j] = tile[k0 + j][dv];
    f16* dst = Vtt + ((size_t)bh * 64 + dv) * 2048 + tb + k0;
    #pragma unroll
    for (int j = 0; j < 4; j++)
      *(half8*)(dst + j * 8) = *(half8*)&buf[j * 8];
  }
}

// ---------------- K head-pack: Kp[tok,512] -> Kpk[bh][tok][64] ----------------
__global__ __launch_bounds__(256) void pack_k(const f16* __restrict__ Kp,
                                              f16* __restrict__ Kpk) {
  int idx = blockIdx.x * 256 + threadIdx.x;  // half8 units
  int dk8 = idx & 7;
  int tok = (idx >> 3) & (SS - 1);
  int bh  = idx >> 14;
  int b = bh >> 3, h = bh & 7;
  *(half8*)&Kpk[(size_t)idx * 8] =
      *(const half8*)&Kp[((size_t)(b * SS + tok)) * 512 + h * 64 + dk8 * 8];
}

// ---------------- attention phases (S^T fragment layout) ----------------
// QK^T computed transposed: sacc[n][m] = mfma(A=K-frag, B=Q-frag) so each
// lane's 4 accum regs hold 4 CONSECUTIVE k indices at a fixed q row:
//   k = wc*64 + n*16 + lg*4 + r,  q = qblk + wr*64 + m*16 + lr
// -> float4 other loads, 4B mask loads, float4 attn stores, half4 Ps writes.
template<int PHASE>
__global__ __launch_bounds__(256, 2) void attn_phase(
    const f16* __restrict__ Qp, const f16* __restrict__ Kpk,
    const f16* __restrict__ Vtt, const float* __restrict__ other,
    const unsigned char* __restrict__ mask8, const int* __restrict__ mask32,
    const unsigned int* __restrict__ flag, float* __restrict__ lsum,
    float* __restrict__ attn_out, f16* __restrict__ ctx) {
  extern __shared__ char smem[];
  f16* Ks = (f16*)smem;                       // [128][72]
  f16* Ps = (f16*)smem;                       // [128][136] (phase2, aliases Ks)
  f16* Vs = (f16*)(smem + 34816);             // [64][136]  (phase2)
  float* red = (PHASE == 1) ? (float*)(smem + 18432) : (float*)(smem + 52224);

  const int t = threadIdx.x;
  const int bh = blockIdx.x;
  const int b = bh >> 3, h = bh & 7;
  const int qblk = blockIdx.y * 128;
  const int w = t >> 6, ln = t & 63;
  const int wr = w >> 1, wc = w & 1;
  const int lr = ln & 15, lg = ln >> 4;
  const bool use8 = (*flag) != 0;

  // Q fragments (B-operand: col = lane&15 -> q row, k-elems = lg*8+j)
  half8 qf[4][2];
  #pragma unroll
  for (int m = 0; m < 4; m++) {
    const f16* qp = Qp + (size_t)(b * SS + qblk + wr * 64 + m * 16 + lr) * 512 + h * 64 + lg * 8;
    qf[m][0] = *(const half8*)qp;
    qf[m][1] = *(const half8*)(qp + 32);
  }

  float rs[4];
  float invl[4];
  if (PHASE == 1) {
    #pragma unroll
    for (int m = 0; m < 4; m++) rs[m] = 0.f;
    if (t < 128) red[t] = 0.f;
  } else {
    if (t < 128) red[t] = 1.0f / lsum[(size_t)bh * SS + qblk + t];
    __syncthreads();
    #pragma unroll
    for (int m = 0; m < 4; m++) invl[m] = red[wr * 64 + m * 16 + lr];
  }
  float4v cacc[2][4] = {};

  for (int kt = 0; kt < 16; kt++) {
    const int kb = kt * 128;
    __syncthreads();  // prev-iter LDS consumers done before restaging
    {
      int sr = t >> 1, c0 = (t & 1) * 32;
      const f16* kp = Kpk + ((size_t)bh * SS + kb + sr) * 64 + c0;
      f16* kd = Ks + sr * 72 + c0;
      *(half8*)(kd)      = *(const half8*)(kp);
      *(half8*)(kd + 8)  = *(const half8*)(kp + 8);
      *(half8*)(kd + 16) = *(const half8*)(kp + 16);
      *(half8*)(kd + 24) = *(const half8*)(kp + 24);
      if (PHASE == 2) {
        int dv = t >> 2, tk = (t & 3) * 32;
        const f16* vp = Vtt + ((size_t)bh * 64 + dv) * 2048 + kb + tk;
        f16* vd = Vs + dv * 136 + tk;
        *(half8*)(vd)      = *(const half8*)(vp);
        *(half8*)(vd + 8)  = *(const half8*)(vp + 8);
        *(half8*)(vd + 16) = *(const half8*)(vp + 16);
        *(half8*)(vd + 24) = *(const half8*)(vp + 24);
      }
    }
    __syncthreads();
    // QK^T transposed: A = K fragment (row = k token), B = Q fragment (col = q)
    float4v sacc[4][4] = {};  // [n (k-frag)][m (q-frag)]
    #pragma unroll
    for (int ks = 0; ks < 2; ks++) {
      half8 kf[4];
      #pragma unroll
      for (int n = 0; n < 4; n++)
        kf[n] = *(const half8*)(Ks + (wc * 64 + n * 16 + lr) * 72 + ks * 32 + lg * 8);
      #pragma unroll
      for (int n = 0; n < 4; n++)
        #pragma unroll
        for (int m = 0; m < 4; m++) sacc[n][m] = mfma16(kf[n], qf[m][ks], sacc[n][m]);
    }
    __syncthreads();  // all Ks reads complete (Ps aliases Ks)
    // epilogue: vectorized scale + bias + mask + exp (+ normalize/store)
    #pragma unroll
    for (int n = 0; n < 4; n++) {
      #pragma unroll
      for (int m = 0; m < 4; m++) {
        const int q_l = wr * 64 + m * 16 + lr;
        const int ql = qblk + q_l;
        const int kc = wc * 64 + n * 16 + lg * 4;
        const size_t oidx = ((size_t)b * SS + ql) * SS + kb + kc;
        float4v oth = *(const float4v*)&other[oidx];
        unsigned int mwb = 0;
        int4v mw4;
        if (use8) mwb = *(const unsigned int*)&mask8[oidx];
        else      mw4 = *(const int4v*)&mask32[oidx];
        if (PHASE == 1) {
          float s = 0.f;
          #pragma unroll
          for (int r = 0; r < 4; r++) {
            float sc = sacc[n][m][r] * 0.125f + oth[r];
            bool mk = use8 ? (((mwb >> (8 * r)) & 0xffu) != 0u) : (mw4[r] != 0);
            s += mk ? 0.0f : __expf(sc);
          }
          rs[m] += s;
        } else {
          float4v av;
          #pragma unroll
          for (int r = 0; r < 4; r++) {
            float sc = sacc[n][m][r] * 0.125f + oth[r];
            bool mk = use8 ? (((mwb >> (8 * r)) & 0xffu) != 0u) : (mw4[r] != 0);
            float p = mk ? 0.0f : __expf(sc);
            av[r] = p * invl[m];
          }
          *(float4v*)&attn_out[((size_t)bh * SS + ql) * SS + kb + kc] = av;
          half4 ph;
          ph[0] = (f16)av[0]; ph[1] = (f16)av[1];
          ph[2] = (f16)av[2]; ph[3] = (f16)av[3];
          *(half4*)&Ps[q_l * 136 + kc] = ph;
        }
      }
    }
    if (PHASE == 2) {
      __syncthreads();  // Ps + Vs ready
      #pragma unroll
      for (int ks = 0; ks < 4; ks++) {
        half8 pf[2], vf[4];
        #pragma unroll
        for (int mm = 0; mm < 2; mm++)
          pf[mm] = *(const half8*)(Ps + (w * 32 + mm * 16 + lr) * 136 + ks * 32 + lg * 8);
        #pragma unroll
        for (int n = 0; n < 4; n++)
          vf[n] = *(const half8*)(Vs + (n * 16 + lr) * 136 + ks * 32 + lg * 8);
        #pragma unroll
        for (int mm = 0; mm < 2; mm++)
          #pragma unroll
          for (int n = 0; n < 4; n++) cacc[mm][n] = mfma16(pf[mm], vf[n], cacc[mm][n]);
      }
    }
  }

  if (PHASE == 1) {
    #pragma unroll
    for (int m = 0; m < 4; m++) {
      float v = rs[m];
      v += __shfl_xor(v, 16);
      v += __shfl_xor(v, 32);
      if (ln < 16) atomicAdd(&red[wr * 64 + m * 16 + lr], v);
    }
    __syncthreads();
    if (t < 128) lsum[(size_t)bh * SS + qblk + t] = red[t];
  } else {
    #pragma unroll
    for (int mm = 0; mm < 2; mm++) {
      #pragma unroll
      for (int n = 0; n < 4; n++) {
        #pragma unroll
        for (int r = 0; r < 4; r++) {
          ctx[(size_t)(b * SS + qblk + w * 32 + mm * 16 + lg * 4 + r) * 512 +
              h * 64 + n * 16 + lr] = (f16)cacc[mm][n][r];
        }
      }
    }
  }
}

extern "C" void kernel_launch(void* const* d_in, const int* in_sizes, int n_in,
                              void* d_out, int out_size, void* d_ws, size_t ws_size,
                              hipStream_t stream) {
  const float* inQ   = (const float*)d_in[0];
  const float* inK   = (const float*)d_in[1];
  const float* inV   = (const float*)d_in[2];
  const void*  mask  = d_in[3];
  const float* other = (const float*)d_in[4];
  const float* WQ    = (const float*)d_in[5];
  const float* WK    = (const float*)d_in[6];
  const float* WV    = (const float*)d_in[7];
  const float* WF    = (const float*)d_in[8];

  char* ws = (char*)d_ws;
  size_t off = 0;
  unsigned int* flag = (unsigned int*)(ws + off); off += 256;
  f16* Qp  = (f16*)(ws + off); off += (size_t)MTOK * 512 * 2;
  f16* Kp  = (f16*)(ws + off); off += (size_t)MTOK * 512 * 2;
  f16* Vp  = (f16*)(ws + off); off += (size_t)MTOK * 512 * 2;  // later reused as Kpk
  f16* Vtt = (f16*)(ws + off); off += (size_t)MTOK * 512 * 2;
  float* lsum = (float*)(ws + off); off += (size_t)BHN * SS * 4;
  f16* ctx = (f16*)(ws + off); off += (size_t)MTOK * 512 * 2;
  if (ws_size < off) return;

  f16* Kpk = Vp;  // Vp is dead after transpose_v

  float* outp  = (float*)d_out;
  float* attnp = outp + (size_t)MTOK * DDIM;

  hipMemsetAsync(flag, 0, 256, stream);
  detect_mask_kernel<<<1, 256, 0, stream>>>((const unsigned int*)mask, flag);

  dim3 pg(64, 4);
  gemm512<0, 1><<<pg, 256, 0, stream>>>(inQ, WQ, Qp);
  gemm512<0, 1><<<pg, 256, 0, stream>>>(inK, WK, Kp);
  gemm512<0, 1><<<pg, 256, 0, stream>>>(inV, WV, Vp);
  transpose_v<<<dim3(32, 16), 256, 0, stream>>>(Vp, Vtt);
  pack_k<<<2048, 256, 0, stream>>>(Kp, Kpk);

  attn_phase<1><<<dim3(32, 16), 256, 18944, stream>>>(
      Qp, Kpk, Vtt, other, (const unsigned char*)mask, (const int*)mask, flag,
      lsum, attnp, ctx);
  attn_phase<2><<<dim3(32, 16), 256, 52736, stream>>>(
      Qp, Kpk, Vtt, other, (const unsigned char*)mask, (const int*)mask, flag,
      lsum, attnp, ctx);

  gemm512<1, 0><<<pg, 256, 0, stream>>>(ctx, WF, outp);
}

// Round 3
// 537.554 us; speedup vs baseline: 3.3956x; 1.7214x over previous
//
#include <hip/hip_runtime.h>

#define BB 4
#define SS 2048
#define DDIM 512
#define HH 8
#define MTOK (BB*SS)   // 8192
#define BHN (BB*HH)    // 32

typedef _Float16 f16;
typedef __attribute__((ext_vector_type(8))) _Float16 half8;
typedef __attribute__((ext_vector_type(4))) _Float16 half4;
typedef __attribute__((ext_vector_type(4))) float float4v;
typedef __attribute__((ext_vector_type(4))) int int4v;
typedef __attribute__((ext_vector_type(4))) unsigned int uint4v;

#define SCALE_L2E 0.180336880073616f   // 0.125 * log2(e)
#define L2E 1.44269504088896f

__device__ __forceinline__ float4v mfma16(half8 a, half8 b, float4v c) {
  return __builtin_amdgcn_mfma_f32_16x16x32_f16(a, b, c, 0, 0, 0);
}

__device__ __forceinline__ half8 cvt8(float4v a, float4v b) {
  half8 r;
  r[0] = (f16)a[0]; r[1] = (f16)a[1]; r[2] = (f16)a[2]; r[3] = (f16)a[3];
  r[4] = (f16)b[0]; r[5] = (f16)b[1]; r[6] = (f16)b[2]; r[7] = (f16)b[3];
  return r;
}

// ---------------- mask dtype detection ----------------
__global__ __launch_bounds__(256) void detect_mask_kernel(
    const unsigned int* __restrict__ m, unsigned int* __restrict__ flag) {
  unsigned int v = 0;
  for (int j = threadIdx.x; j < 65536; j += 256)
    if (m[j] > 1u) v = 1u;
  if (v) atomicOr(flag, 1u);
}

// ---------------- GEMM: [8192,512] x [512,512]^T ----------------
// AMODE 0: A fp32 [tok][512].  AMODE 1: A = ctx2 halves f16 (sum while staging).
// OUTMODE 0: f32 [tok][512]; 1: f16 [tok][512]; 2: Kpk [bh][tok][64];
// 3: Vtt [bh][dv][tok].
template<int AMODE, int OUTMODE>
__global__ __launch_bounds__(256) void gemm512(const void* __restrict__ Ain,
                                               const float* __restrict__ W,
                                               void* __restrict__ Outv) {
  __shared__ f16 As[128][40];
  __shared__ f16 Bs[128][40];
  const int t = threadIdx.x;
  const int bm = blockIdx.x * 128;
  const int bn = blockIdx.y * 128;
  const int w = t >> 6, ln = t & 63;
  const int wr = w >> 1, wc = w & 1;
  const int lr = ln & 15, lg = ln >> 4;
  const int srow = t >> 1, scol = (t & 1) * 16;

  float4v acc[4][4] = {};

  for (int k0 = 0; k0 < 512; k0 += 32) {
    if (AMODE == 1) {
      const f16* ap = (const f16*)Ain + (size_t)(bm + srow) * 512 + k0 + scol;
      const f16* ap2 = ap + (size_t)MTOK * 512;
      half8 x0 = *(const half8*)(ap),      x1 = *(const half8*)(ap + 8);
      half8 y0 = *(const half8*)(ap2),     y1 = *(const half8*)(ap2 + 8);
      *(half8*)&As[srow][scol]     = x0 + y0;
      *(half8*)&As[srow][scol + 8] = x1 + y1;
    } else {
      const float* ap = (const float*)Ain + (size_t)(bm + srow) * 512 + k0 + scol;
      float4v x0 = *(const float4v*)ap,       x1 = *(const float4v*)(ap + 4);
      float4v x2 = *(const float4v*)(ap + 8), x3 = *(const float4v*)(ap + 12);
      *(half8*)&As[srow][scol]     = cvt8(x0, x1);
      *(half8*)&As[srow][scol + 8] = cvt8(x2, x3);
    }
    {
      const float* wp = W + (size_t)(bn + srow) * 512 + k0 + scol;
      float4v x0 = *(const float4v*)wp,       x1 = *(const float4v*)(wp + 4);
      float4v x2 = *(const float4v*)(wp + 8), x3 = *(const float4v*)(wp + 12);
      *(half8*)&Bs[srow][scol]     = cvt8(x0, x1);
      *(half8*)&Bs[srow][scol + 8] = cvt8(x2, x3);
    }
    __syncthreads();
    half8 af[4], bf[4];
    #pragma unroll
    for (int m = 0; m < 4; m++) af[m] = *(const half8*)&As[wr * 64 + m * 16 + lr][lg * 8];
    #pragma unroll
    for (int n = 0; n < 4; n++) bf[n] = *(const half8*)&Bs[wc * 64 + n * 16 + lr][lg * 8];
    #pragma unroll
    for (int m = 0; m < 4; m++)
      #pragma unroll
      for (int n = 0; n < 4; n++) acc[m][n] = mfma16(af[m], bf[n], acc[m][n]);
    __syncthreads();
  }

  #pragma unroll
  for (int m = 0; m < 4; m++) {
    int row = bm + wr * 64 + m * 16 + lg * 4;
    #pragma unroll
    for (int n = 0; n < 4; n++) {
      int col = bn + wc * 64 + n * 16 + lr;
      if (OUTMODE == 0) {
        #pragma unroll
        for (int r = 0; r < 4; r++)
          ((float*)Outv)[(size_t)(row + r) * 512 + col] = acc[m][n][r];
      } else if (OUTMODE == 1) {
        #pragma unroll
        for (int r = 0; r < 4; r++)
          ((f16*)Outv)[(size_t)(row + r) * 512 + col] = (f16)acc[m][n][r];
      } else if (OUTMODE == 2) {
        // Kpk[bh][tok][64]
        int b_ = row >> 11, s_ = row & 2047, h_ = col >> 6, dk_ = col & 63;
        #pragma unroll
        for (int r = 0; r < 4; r++)
          ((f16*)Outv)[(((size_t)(b_ * 8 + h_)) * SS + s_ + r) * 64 + dk_] =
              (f16)acc[m][n][r];
      } else {
        // Vtt[bh][dv][tok] - 4 consecutive tok -> half4 store
        int b_ = row >> 11, s_ = row & 2047, h_ = col >> 6, dv_ = col & 63;
        half4 ph;
        ph[0] = (f16)acc[m][n][0]; ph[1] = (f16)acc[m][n][1];
        ph[2] = (f16)acc[m][n][2]; ph[3] = (f16)acc[m][n][3];
        *(half4*)&((f16*)Outv)[(((size_t)(b_ * 8 + h_)) * 64 + dv_) * SS + s_] = ph;
      }
    }
  }
}

// ---------------- fused attention, heads inner-looped ----------------
// Block = (b, 32 q-rows, k-half).  grid 512, bid%8 -> (b, kh) so each XCD's
// L2 holds one (b,kh) K+V slice (2 MB).  Per kt: stage other+mask tile once
// (as log2e-scaled, -1e9-masked fp32), then loop 8 heads staging K/V.
// PHASE 1: row sums (partial per k-half) -> lsum2[kh].
// PHASE 2: normalized attn writes + PV -> ctx2[kh] (f16 partial).
template<int PHASE>
__global__ __launch_bounds__(256, 2) void attn_fused(
    const f16* __restrict__ Qp, const f16* __restrict__ Kpk,
    const f16* __restrict__ Vtt, const float* __restrict__ other,
    const unsigned char* __restrict__ mask8, const int* __restrict__ mask32,
    const unsigned int* __restrict__ flag, float* __restrict__ lsum2,
    float* __restrict__ attn_out, f16* __restrict__ ctx2) {
  extern __shared__ char smem[];
  float* othm = (float*)smem;                 // [32][132]  16896 B
  f16* Ks = (f16*)(smem + 16896);             // [128][72]  18432 B
  f16* Vs = (f16*)(smem + 35328);             // [64][136]  (PHASE2)
  f16* Ps = (f16*)(smem + 52736);             // [32][136]  (PHASE2)
  float* red = (float*)(smem + 35328);        // [4][8][32] (PHASE1)

  const int t = threadIdx.x;
  const int bid = blockIdx.x;
  const int b  = (bid & 7) >> 1;
  const int kh = bid & 1;
  const int qblk = (bid >> 3) * 32;
  const int w = t >> 6, ln = t & 63;
  const int lr = ln & 15, lg = ln >> 4;
  const bool use8 = (*flag) != 0;

  float invl[8][2];
  if (PHASE == 2) {
    #pragma unroll
    for (int h = 0; h < 8; h++) {
      #pragma unroll
      for (int m = 0; m < 2; m++) {
        size_t qi = (size_t)(b * 8 + h) * SS + qblk + m * 16 + lr;
        float l = lsum2[qi] + lsum2[(size_t)BHN * SS + qi];
        invl[h][m] = 1.0f / l;
      }
    }
  }

  float rs[8][2];
  float4v cacc[8][2] = {};
  #pragma unroll
  for (int h = 0; h < 8; h++) { rs[h][0] = 0.f; rs[h][1] = 0.f; }

  const int kt0 = kh * 8;
  for (int kti = 0; kti < 8; kti++) {
    const int kb = (kt0 + kti) * 128;
    // ---- stage other+mask tile (once per kt, reused by all 8 heads) ----
    {
      const int q = t >> 3, k0 = (t & 7) * 16;
      const size_t base = ((size_t)b * SS + qblk + q) * SS + kb + k0;
      const float* op = other + base;
      float4v o[4];
      #pragma unroll
      for (int j = 0; j < 4; j++) o[j] = *(const float4v*)(op + j * 4);
      float* od = othm + q * 132 + k0;
      if (use8) {
        uint4v mv = *(const uint4v*)(mask8 + base);
        #pragma unroll
        for (int j = 0; j < 4; j++) {
          unsigned int mm = mv[j];
          float4v r;
          #pragma unroll
          for (int rr = 0; rr < 4; rr++)
            r[rr] = ((mm >> (8 * rr)) & 0xffu) ? -1e9f : o[j][rr] * L2E;
          *(float4v*)(od + j * 4) = r;
        }
      } else {
        #pragma unroll
        for (int j = 0; j < 4; j++) {
          int4v m4 = *(const int4v*)(mask32 + base + j * 4);
          float4v r;
          #pragma unroll
          for (int rr = 0; rr < 4; rr++)
            r[rr] = m4[rr] ? -1e9f : o[j][rr] * L2E;
          *(float4v*)(od + j * 4) = r;
        }
      }
    }
    for (int h = 0; h < 8; h++) {
      // Q fragments (global, L2-hot) - issue early
      half8 qf[2][2];
      #pragma unroll
      for (int m = 0; m < 2; m++) {
        const f16* qp = Qp + ((size_t)b * SS + qblk + m * 16 + lr) * 512 + h * 64 + lg * 8;
        qf[m][0] = *(const half8*)qp;
        qf[m][1] = *(const half8*)(qp + 32);
      }
      // stage K (and V)
      {
        const int sr = t >> 1, c0 = (t & 1) * 32;
        const f16* kp = Kpk + ((size_t)(b * 8 + h) * SS + kb + sr) * 64 + c0;
        f16* kd = Ks + sr * 72 + c0;
        *(half8*)(kd)      = *(const half8*)(kp);
        *(half8*)(kd + 8)  = *(const half8*)(kp + 8);
        *(half8*)(kd + 16) = *(const half8*)(kp + 16);
        *(half8*)(kd + 24) = *(const half8*)(kp + 24);
      }
      if (PHASE == 2) {
        const int dv = t >> 2, tk = (t & 3) * 32;
        const f16* vp = Vtt + ((size_t)(b * 8 + h) * 64 + dv) * SS + kb + tk;
        f16* vd = Vs + dv * 136 + tk;
        *(half8*)(vd)      = *(const half8*)(vp);
        *(half8*)(vd + 8)  = *(const half8*)(vp + 8);
        *(half8*)(vd + 16) = *(const half8*)(vp + 16);
        *(half8*)(vd + 24) = *(const half8*)(vp + 24);
      }
      __syncthreads();  // K/V (and othm on first h) ready
      // ---- QK^T (transposed: A=K rows=k-token, B=Q cols=q) ----
      float4v sacc[2][2] = {};  // [n (k)][m (q)]
      #pragma unroll
      for (int ks = 0; ks < 2; ks++) {
        half8 kf[2];
        #pragma unroll
        for (int n = 0; n < 2; n++)
          kf[n] = *(const half8*)(Ks + (w * 32 + n * 16 + lr) * 72 + ks * 32 + lg * 8);
        #pragma unroll
        for (int n = 0; n < 2; n++)
          #pragma unroll
          for (int m = 0; m < 2; m++) sacc[n][m] = mfma16(kf[n], qf[m][ks], sacc[n][m]);
      }
      // ---- epilogue ----
      #pragma unroll
      for (int n = 0; n < 2; n++) {
        #pragma unroll
        for (int m = 0; m < 2; m++) {
          const int q_l = m * 16 + lr;
          const int kc = w * 32 + n * 16 + lg * 4;
          float4v oth = *(const float4v*)(othm + q_l * 132 + kc);
          if (PHASE == 1) {
            float s = 0.f;
            #pragma unroll
            for (int r = 0; r < 4; r++)
              s += exp2f(fmaf(sacc[n][m][r], SCALE_L2E, oth[r]));
            rs[h][m] += s;
          } else {
            float4v av;
            #pragma unroll
            for (int r = 0; r < 4; r++)
              av[r] = exp2f(fmaf(sacc[n][m][r], SCALE_L2E, oth[r])) * invl[h][m];
            *(float4v*)&attn_out[((size_t)(b * 8 + h) * SS + qblk + q_l) * SS + kb + kc] = av;
            half4 ph;
            ph[0] = (f16)av[0]; ph[1] = (f16)av[1];
            ph[2] = (f16)av[2]; ph[3] = (f16)av[3];
            *(half4*)(Ps + q_l * 136 + kc) = ph;
          }
        }
      }
      if (PHASE == 2) {
        __syncthreads();  // Ps complete
        const int qw = w & 1, dvb = (w >> 1) * 32;
        #pragma unroll
        for (int ks = 0; ks < 4; ks++) {
          half8 pf = *(const half8*)(Ps + (qw * 16 + lr) * 136 + ks * 32 + lg * 8);
          #pragma unroll
          for (int n = 0; n < 2; n++) {
            half8 vf = *(const half8*)(Vs + (dvb + n * 16 + lr) * 136 + ks * 32 + lg * 8);
            cacc[h][n] = mfma16(pf, vf, cacc[h][n]);
          }
        }
      }
      __syncthreads();  // consumers done before next head restages / next kt othm
    }
  }

  if (PHASE == 1) {
    #pragma unroll
    for (int h = 0; h < 8; h++) {
      #pragma unroll
      for (int m = 0; m < 2; m++) {
        float v = rs[h][m];
        v += __shfl_xor(v, 16);
        v += __shfl_xor(v, 32);
        if (ln < 16) red[(w * 8 + h) * 32 + m * 16 + lr] = v;
      }
    }
    __syncthreads();
    {
      const int h = t >> 5, q = t & 31;
      float tot = red[(0 + h) * 32 + q] + red[(8 + h) * 32 + q] +
                  red[(16 + h) * 32 + q] + red[(24 + h) * 32 + q];
      lsum2[(size_t)kh * BHN * SS + (size_t)(b * 8 + h) * SS + qblk + q] = tot;
    }
  } else {
    const int qw = w & 1, dvb = (w >> 1) * 32;
    #pragma unroll
    for (int h = 0; h < 8; h++) {
      #pragma unroll
      for (int n = 0; n < 2; n++) {
        #pragma unroll
        for (int r = 0; r < 4; r++) {
          ctx2[(size_t)kh * MTOK * 512 +
               ((size_t)b * SS + qblk + qw * 16 + lg * 4 + r) * 512 +
               h * 64 + dvb + n * 16 + lr] = (f16)cacc[h][n][r];
        }
      }
    }
  }
}

extern "C" void kernel_launch(void* const* d_in, const int* in_sizes, int n_in,
                              void* d_out, int out_size, void* d_ws, size_t ws_size,
                              hipStream_t stream) {
  const float* inQ   = (const float*)d_in[0];
  const float* inK   = (const float*)d_in[1];
  const float* inV   = (const float*)d_in[2];
  const void*  mask  = d_in[3];
  const float* other = (const float*)d_in[4];
  const float* WQ    = (const float*)d_in[5];
  const float* WK    = (const float*)d_in[6];
  const float* WV    = (const float*)d_in[7];
  const float* WF    = (const float*)d_in[8];

  char* ws = (char*)d_ws;
  size_t off = 0;
  unsigned int* flag = (unsigned int*)(ws + off); off += 256;
  f16* Qp    = (f16*)(ws + off); off += (size_t)MTOK * 512 * 2;
  f16* Kpk   = (f16*)(ws + off); off += (size_t)MTOK * 512 * 2;
  f16* Vtt   = (f16*)(ws + off); off += (size_t)MTOK * 512 * 2;
  float* lsum2 = (float*)(ws + off); off += (size_t)2 * BHN * SS * 4;
  f16* ctx2  = (f16*)(ws + off); off += (size_t)2 * MTOK * 512 * 2;
  if (ws_size < off) return;

  float* outp  = (float*)d_out;
  float* attnp = outp + (size_t)MTOK * DDIM;

  hipMemsetAsync(flag, 0, 256, stream);
  detect_mask_kernel<<<1, 256, 0, stream>>>((const unsigned int*)mask, flag);

  dim3 pg(64, 4);
  gemm512<0, 1><<<pg, 256, 0, stream>>>(inQ, WQ, Qp);
  gemm512<0, 2><<<pg, 256, 0, stream>>>(inK, WK, Kpk);
  gemm512<0, 3><<<pg, 256, 0, stream>>>(inV, WV, Vtt);

  attn_fused<1><<<512, 256, 39424, stream>>>(
      Qp, Kpk, Vtt, other, (const unsigned char*)mask, (const int*)mask, flag,
      lsum2, attnp, ctx2);
  attn_fused<2><<<512, 256, 61440, stream>>>(
      Qp, Kpk, Vtt, other, (const unsigned char*)mask, (const int*)mask, flag,
      lsum2, attnp, ctx2);

  gemm512<1, 0><<<pg, 256, 0, stream>>>(ctx2, WF, outp);
}